// Round 3
// baseline (263.140 us; speedup 1.0000x reference)
//
#include <hip/hip_runtime.h>
#include <hip/hip_bf16.h>

#define H_ 64
#define FF_ 128
#define V_ 64
#define B_ 256
#define L_ 4096
#define T_ (L_ - 1)   // 4095 scan steps (tokens 0..4094); token 4095 -> q

__device__ __forceinline__ float wsum64(float x) {
  #pragma unroll
  for (int m = 32; m; m >>= 1) x += __shfl_xor(x, m, 64);
  return x;
}

__device__ __forceinline__ float readlane_f(float x, int lane) {
  return __int_as_float(__builtin_amdgcn_readlane(__float_as_int(x), lane));
}

// ---------------------------------------------------------------------------
// Kernel 1: per-token-id tables. tok = blockIdx, lane = feature index.
// kv_table[tok][j] = (kn_j, v_j); q_table[tok][j] = q_j.
// ---------------------------------------------------------------------------
__global__ __launch_bounds__(64) void build_tables(
    const float* __restrict__ embed, const float* __restrict__ W1,
    const float* __restrict__ b1, const float* __restrict__ W2,
    const float* __restrict__ b2, const float* __restrict__ gamma,
    const float* __restrict__ beta, const float* __restrict__ Wk,
    const float* __restrict__ Wv, const float* __restrict__ Wq,
    float2* __restrict__ kv_table, float* __restrict__ q_table)
{
  const int tok = blockIdx.x;
  const int l = threadIdx.x;
  __shared__ float sh_h[H_];
  __shared__ float sh_a[FF_];
  __shared__ float sh_n[H_];

  float h = embed[tok * H_ + l];
  sh_h[l] = h;
  __syncthreads();

  // a = relu(h @ W1 + b1), FF=128 -> 2 outputs per lane
  float a0 = b1[l], a1 = b1[l + 64];
  #pragma unroll 8
  for (int j = 0; j < H_; ++j) {
    float hj = sh_h[j];
    a0 = fmaf(hj, W1[j * FF_ + l], a0);
    a1 = fmaf(hj, W1[j * FF_ + l + 64], a1);
  }
  sh_a[l]      = fmaxf(a0, 0.f);
  sh_a[l + 64] = fmaxf(a1, 0.f);
  __syncthreads();

  // x = h + a @ W2 + b2
  float x = h + b2[l];
  #pragma unroll 8
  for (int f = 0; f < FF_; ++f) x = fmaf(sh_a[f], W2[f * H_ + l], x);

  // LayerNorm over H
  float mu = wsum64(x) * (1.0f / 64.0f);
  float d = x - mu;
  float var = wsum64(d * d) * (1.0f / 64.0f);
  float hn = d * rsqrtf(var + 1e-5f) * gamma[l] + beta[l];
  sh_n[l] = hn;
  __syncthreads();

  float k = 0.f, v = 0.f, q = 0.f;
  #pragma unroll 8
  for (int i = 0; i < H_; ++i) {
    float hi = sh_n[i];
    k = fmaf(hi, Wk[i * H_ + l], k);
    v = fmaf(hi, Wv[i * H_ + l], v);
    q = fmaf(hi, Wq[i * H_ + l], q);
  }
  float n2 = wsum64(k * k);
  float kn = k / fmaxf(sqrtf(n2), 1e-12f);
  kv_table[tok * H_ + l] = make_float2(kn, v);
  q_table[tok * H_ + l] = q;
}

// ---------------------------------------------------------------------------
// Kernel 2: Gram[a][j] = kn_a . kn_j  (64x64)
// ---------------------------------------------------------------------------
__global__ __launch_bounds__(64) void build_gram(
    const float2* __restrict__ kv_table, float* __restrict__ gram)
{
  const int arow = blockIdx.x;
  const int j = threadIdx.x;
  float s = 0.f;
  #pragma unroll 8
  for (int i = 0; i < H_; ++i)
    s = fmaf(kv_table[arow * H_ + i].x, kv_table[j * H_ + i].x, s);
  gram[arow * H_ + j] = s;
}

// ---------------------------------------------------------------------------
// Kernel 3: per-batch backward vector scan in "a-space".
//   a_j = kn_vocab[j] . z   (z starts at q, never materialized)
//   step t: c = a[s_t]; r += c * v[s_t]; a -= c * Gram[s_t][:]
// grouped 4 steps per round:
//   d_g = a[s_g] (pre-group), c_g = d_g - sum_{h<g} c_h * Gram[s_g][s_h]
// then: out = (r @ Wr + br) @ Wo + bo
// ---------------------------------------------------------------------------
__global__ __launch_bounds__(64) void scan_kernel(
    const int* __restrict__ seq, const float2* __restrict__ kv_table,
    const float* __restrict__ q_table, const float* __restrict__ gram,
    const float* __restrict__ Wr, const float* __restrict__ br,
    const float* __restrict__ Wo, const float* __restrict__ bo,
    float* __restrict__ out)
{
  const int b = blockIdx.x;
  const int l = threadIdx.x;

  __shared__ __align__(16) int stok[L_];       // 16 KB: whole sequence
  __shared__ float kn_s[H_ * 65];              // padded rows, stride 65
  __shared__ float v_s[V_ * H_];               // 16 KB, broadcast-row reads
  __shared__ float g_s[V_ * V_];               // 16 KB Gram, broadcast-row reads
  __shared__ float qs[H_];
  __shared__ float sh_r[H_];
  __shared__ float sh_rr[H_];

  // stage tables + sequence
  for (int idx = l; idx < V_ * H_; idx += 64) {
    float2 t = kv_table[idx];
    kn_s[(idx >> 6) * 65 + (idx & 63)] = t.x;
    v_s[idx] = t.y;
    g_s[idx] = gram[idx];
  }
  for (int idx = l; idx < L_; idx += 64) stok[idx] = seq[b * L_ + idx];
  __syncthreads();

  const int tq = stok[L_ - 1];
  qs[l] = q_table[tq * H_ + l];
  __syncthreads();

  // a_l = kn_vocab[l] . q   (per-lane row of padded kn_s: 2-way banks = free)
  float a = 0.f;
  #pragma unroll 8
  for (int i = 0; i < H_; ++i) a = fmaf(kn_s[l * 65 + i], qs[i], a);

  float r = 0.f;

  // remainder: steps t = 4094, 4093, 4092 (4095 = 3 + 4*1023)
  for (int t = T_ - 1; t >= 4092; --t) {
    int s0 = __builtin_amdgcn_readfirstlane(stok[t]);
    float c0 = readlane_f(a, s0);
    a = fmaf(-c0, g_s[s0 * 64 + l], a);
    r = fmaf(c0, v_s[s0 * 64 + l], r);
  }

  // main loop: groups of 4, descending t; stok[t-3..t] is 16B-aligned
  #pragma unroll 2
  for (int t = 4091; t >= 3; t -= 4) {
    int4 tv = *reinterpret_cast<const int4*>(&stok[t - 3]);
    int s0 = __builtin_amdgcn_readfirstlane(tv.w);  // step t (first)
    int s1 = __builtin_amdgcn_readfirstlane(tv.z);  // step t-1
    int s2 = __builtin_amdgcn_readfirstlane(tv.y);  // step t-2
    int s3 = __builtin_amdgcn_readfirstlane(tv.x);  // step t-3

    // Gram rows (needed for the a-update anyway)
    float gr0 = g_s[s0 * 64 + l];
    float gr1 = g_s[s1 * 64 + l];
    float gr2 = g_s[s2 * 64 + l];
    float gr3 = g_s[s3 * 64 + l];

    // candidate dots on the pre-group a
    float d0 = readlane_f(a, s0);
    float d1 = readlane_f(a, s1);
    float d2 = readlane_f(a, s2);
    float d3 = readlane_f(a, s3);

    // Gram scalars via readlane on the rows (no extra LDS traffic)
    float g10 = readlane_f(gr1, s0);
    float g20 = readlane_f(gr2, s0);
    float g21 = readlane_f(gr2, s1);
    float g30 = readlane_f(gr3, s0);
    float g31 = readlane_f(gr3, s1);
    float g32 = readlane_f(gr3, s2);

    // triangular fixup (exact algebra, any token repeats allowed)
    float c0 = d0;
    float c1 = fmaf(-c0, g10, d1);
    float c2 = fmaf(-c1, g21, fmaf(-c0, g20, d2));
    float c3 = fmaf(-c2, g32, fmaf(-c1, g31, fmaf(-c0, g30, d3)));

    // apply combined rank-4 update to a
    a = fmaf(-c0, gr0, a);
    a = fmaf(-c1, gr1, a);
    a = fmaf(-c2, gr2, a);
    a = fmaf(-c3, gr3, a);

    // accumulate r (off critical path)
    r = fmaf(c0, v_s[s0 * 64 + l], r);
    r = fmaf(c1, v_s[s1 * 64 + l], r);
    r = fmaf(c2, v_s[s2 * 64 + l], r);
    r = fmaf(c3, v_s[s3 * 64 + l], r);
  }

  // tail: out = (r @ Wr + br) @ Wo + bo
  sh_r[l] = r;
  __syncthreads();
  float rr = br[l];
  #pragma unroll 8
  for (int i = 0; i < H_; ++i) rr = fmaf(sh_r[i], Wr[i * H_ + l], rr);
  sh_rr[l] = rr;
  __syncthreads();
  float o = bo[l];
  #pragma unroll 8
  for (int j = 0; j < H_; ++j) o = fmaf(sh_rr[j], Wo[j * V_ + l], o);
  out[b * V_ + l] = o;
}

extern "C" void kernel_launch(void* const* d_in, const int* in_sizes, int n_in,
                              void* d_out, int out_size, void* d_ws, size_t ws_size,
                              hipStream_t stream) {
  const int*   seq   = (const int*)  d_in[0];
  const float* embed = (const float*)d_in[1];
  const float* W1    = (const float*)d_in[2];
  const float* b1    = (const float*)d_in[3];
  const float* W2    = (const float*)d_in[4];
  const float* b2    = (const float*)d_in[5];
  const float* gamma = (const float*)d_in[6];
  const float* beta  = (const float*)d_in[7];
  const float* Wk    = (const float*)d_in[8];
  const float* Wv    = (const float*)d_in[9];
  const float* Wq    = (const float*)d_in[10];
  const float* Wr    = (const float*)d_in[11];
  const float* br    = (const float*)d_in[12];
  const float* Wo    = (const float*)d_in[13];
  const float* bo    = (const float*)d_in[14];
  float* out = (float*)d_out;

  float2* kv_table = (float2*)d_ws;                    // 32 KB
  float*  q_table  = (float*)((char*)d_ws + 32 * 1024); // 16 KB
  float*  gram     = (float*)((char*)d_ws + 48 * 1024); // 16 KB

  build_tables<<<V_, 64, 0, stream>>>(embed, W1, b1, W2, b2, gamma, beta,
                                      Wk, Wv, Wq, kv_table, q_table);
  build_gram<<<V_, 64, 0, stream>>>(kv_table, gram);
  scan_kernel<<<B_, 64, 0, stream>>>(seq, kv_table, q_table, gram,
                                     Wr, br, Wo, bo, out);
}